// Round 12
// baseline (116.742 us; speedup 1.0000x reference)
//
#include <hip/hip_runtime.h>

typedef __attribute__((ext_vector_type(4))) float f32x4;
typedef __attribute__((ext_vector_type(8))) short short8;
typedef unsigned short ushort_t;

constexpr int DM = 1024, DH = 64, S = 4096, B = 4;
// fold softmax scale 1/sqrt(64) AND log2(e) into Q so scores are in exp2 units
constexpr float QSCALE = 0.125f * 1.44269504088896340736f;
constexpr int SPLIT = 4;

// ws layout (bytes)
constexpr size_t WBT_OFF = 0;                    // Wbt: [192][1024] bf16 (W transposed)
constexpr size_t QB_OFF  = 393216;               // Qb:  [B*S][64] bf16, pre-scaled
constexpr size_t KB_OFF  = QB_OFF + 2097152;     // Kb:  [B*S][64] bf16, LINEAR
constexpr size_t VT_OFF  = KB_OFF + 2097152;     // Vtb: [B][64][S] bf16, LINEAR
constexpr size_t ML_OFF  = VT_OFF + 2097152;     // ml:  f32 [4][B*S][2]  = 512KB
constexpr size_t PO_OFF  = ML_OFF + 524288;      // po:  bf16 [4][B*S][64] = 8MB

__device__ __forceinline__ ushort_t f2bf(float f) {  // RNE f32->bf16
    unsigned u = __float_as_uint(f);
    u += 0x7FFFu + ((u >> 16) & 1u);
    return (ushort_t)(u >> 16);
}

__device__ __forceinline__ void gl_lds16(const void* g, void* l) {
    __builtin_amdgcn_global_load_lds(
        (const __attribute__((address_space(1))) unsigned int*)g,
        (__attribute__((address_space(3))) unsigned int*)l, 16, 0, 0);
}

// ---------------- prep: W fp32 [1024][64] -> Wbt bf16 [192][1024] (transposed) ----
__global__ __launch_bounds__(256) void prep_w_kernel(
    const float* __restrict__ Wq, const float* __restrict__ Wk,
    const float* __restrict__ Wv, ushort_t* __restrict__ wbt)
{
    const int n = blockIdx.x;            // 0..191 : [Q(0-63)|K(64-127)|V(128-191)]
    const int p = n >> 6, d = n & 63;
    const float* W = (p == 0) ? Wq : (p == 1) ? Wk : Wv;
    const int k0 = threadIdx.x * 4;
    ushort4 pack;
    pack.x = f2bf(W[(k0 + 0) * DH + d]);
    pack.y = f2bf(W[(k0 + 1) * DH + d]);
    pack.z = f2bf(W[(k0 + 2) * DH + d]);
    pack.w = f2bf(W[(k0 + 3) * DH + d]);
    *reinterpret_cast<ushort4*>(wbt + (size_t)n * DM + k0) = pack;
}

// ---------------- QKV projection: T4 counted-vmcnt pipelined GEMM ----------------
// Block = 512 thr (8 waves) on 32 rows; wave = (sub = m-half, np = n-quarter).
// A: register-direct per lane (lane owns row sub*16+q16, 8 k-vals via 2 float4).
// B: quad-buffered 12KB stages via global_load_lds, issued TWO steps ahead;
// s_waitcnt vmcnt(4) + raw s_barrier per step -> next stages stay in flight
// across the barrier (T4). vmcnt(4) is placement-robust: st(s) always has >=4
// younger gl_lds (st(s+1),st(s+2)); 4-buffer rotation is race-free for the
// <=1-barrier wave skew. Staging is wave-uniform (2 gl_lds each; segs 8-11
// duplicated by waves 4-7 with identical data - benign).
__global__ __launch_bounds__(512, 4) void qkv_mfma_kernel(
    const float* __restrict__ x, const ushort_t* __restrict__ wbt,
    const float* __restrict__ bq, const float* __restrict__ bk,
    const float* __restrict__ bv,
    ushort_t* __restrict__ qb, ushort_t* __restrict__ kb, ushort_t* __restrict__ vt)
{
    __shared__ uint4 BsU[4][768];        // 4 x 12KB quad-buffer: [192 n][64B] per step

    const int tid = threadIdx.x;
    const int wid = tid >> 6, lane = tid & 63;
    const int q16 = lane & 15, lg = lane >> 4;
    const int sub = wid & 1, np = wid >> 1;
    const int r0 = blockIdx.x * 32;
    const char* wB = (const char*)wbt;

    const float* xr = x + (size_t)(r0 + sub * 16 + q16) * DM + lg * 8;

    const int sgA = wid, sgB = (wid & 3) + 8;
    auto stageB = [&](int kk, int buf) {
        gl_lds16(wB + (size_t)(sgA * 16 + (lane >> 2)) * 2048 + kk * 2
                    + ((((lane & 3) ^ ((lane >> 2) & 3))) << 4),
                 (char*)&BsU[buf][0] + sgA * 1024 + lane * 16);
        gl_lds16(wB + (size_t)(sgB * 16 + (lane >> 2)) * 2048 + kk * 2
                    + ((((lane & 3) ^ ((lane >> 2) & 3))) << 4),
                 (char*)&BsU[buf][0] + sgB * 1024 + lane * 16);
    };

    f32x4 acc[3];
#pragma unroll
    for (int j = 0; j < 3; ++j) acc[j] = {0.f, 0.f, 0.f, 0.f};

    // prologue: A(0) to regs; stage steps 0,1
    float4 apA = *(const float4*)(xr + 0);
    float4 apB = *(const float4*)(xr + 4);
    stageB(0, 0);
    stageB(32, 1);

    for (int s = 0; s < 32; ++s) {
        const int sn = (s + 1 < 32) ? (s + 1) : 31;     // clamped: keeps vmcnt uniform
        const int sp = (s + 2 < 32) ? (s + 2) : 31;     // clamped stage (dead buffer)
        const float4 anA = *(const float4*)(xr + sn * 32);
        const float4 anB = *(const float4*)(xr + sn * 32 + 4);
        stageB(sp * 32, (s + 2) & 3);

        asm volatile("s_waitcnt vmcnt(4)" ::: "memory");   // st(s) done; st(s+1/2) in flight
        __builtin_amdgcn_sched_barrier(0);
        __builtin_amdgcn_s_barrier();                       // all waves' st(s) visible
        __builtin_amdgcn_sched_barrier(0);

        short8 Af;
        Af[0] = (short)f2bf(apA.x); Af[1] = (short)f2bf(apA.y);
        Af[2] = (short)f2bf(apA.z); Af[3] = (short)f2bf(apA.w);
        Af[4] = (short)f2bf(apB.x); Af[5] = (short)f2bf(apB.y);
        Af[6] = (short)f2bf(apB.z); Af[7] = (short)f2bf(apB.w);

        const char* BsC = (const char*)&BsU[s & 3][0];
        __builtin_amdgcn_s_setprio(1);
#pragma unroll
        for (int j = 0; j < 3; ++j) {
            const int nt = np * 3 + j;
            const short8 Bf = *(const short8*)(
                BsC + (nt * 16 + q16) * 64 + ((lg ^ (q16 & 3)) << 4));
            acc[j] = __builtin_amdgcn_mfma_f32_16x16x32_bf16(Af, Bf, acc[j], 0, 0, 0);
        }
        __builtin_amdgcn_s_setprio(0);
        apA = anA; apB = anB;
    }

    // Epilogue: C/D layout row=(lane>>4)*4+reg, col=lane&15. Kb/Vt LINEAR.
#pragma unroll
    for (int j = 0; j < 3; ++j) {
        const int nt = np * 3 + j;
        const int p = nt >> 2, d = ((nt & 3) << 4) + q16;
        const float* bp = (p == 0) ? bq : (p == 1) ? bk : bv;
        const float bb = bp[d];
#pragma unroll
        for (int r = 0; r < 4; ++r) {
            const int m = r0 + sub * 16 + (lg << 2) + r;
            const float v = acc[j][r] + bb;
            if (p == 0) {
                qb[(size_t)m * 64 + d] = f2bf(v * QSCALE);
            } else if (p == 1) {
                kb[(size_t)m * 64 + d] = f2bf(v);
            } else {
                const int bb_ = m >> 12, sx = m & 4095;
                vt[(size_t)bb_ * 262144 + (size_t)d * 4096 + sx] = f2bf(v);
            }
        }
    }
}

// ---------------- causal flash attention: QBLK=64, KVBLK=128, V-direct ----------
// R10 structure, but V is NOT staged in LDS: Vt rows are the PV B-fragments and
// read fully-coalesced from L2 (proven R6). LDS = K dbuf 32KB + P 16KB = 48KB
// -> 3 blocks/CU (was 2). V loads 2-deep staggered (va/vb) so L2 latency hides
// under softmax/PV. launch_bounds(256,3) raises VGPR cap to fit va/vb.
__global__ __launch_bounds__(256, 3) void attn_mfma_kernel(
    const ushort_t* __restrict__ qb, const ushort_t* __restrict__ kb,
    const ushort_t* __restrict__ vt, ushort_t* __restrict__ po,
    float* __restrict__ ml)
{
    __shared__ uint4 LsU[2][1024];     // 32KB: [buf][K: 128 rows x 128B]
    __shared__ uint4 PsU[4][256];      // 16KB: per-wave P [16 q][128 kv] bf16

    const int tid = threadIdx.x;
    const int wid = tid >> 6, lane = tid & 63;
    const int q16 = lane & 15, lg = lane >> 4;
    const int z = blockIdx.y;

    // XCD-pinned (2 XCDs per batch), heavy q-blocks first.
    const int linear = blockIdx.x;            // 0..255
    const int xcd = linear & 7, idx = linear >> 3;
    const int b = xcd >> 1;
    const int qt = 63 - (idx * 2 + (xcd & 1));   // 64-row q-block, 0..63

    const int qrow = qt * 64 + wid * 16 + q16;   // this lane's q (C/D column)
    const ushort_t* Qb = qb + (size_t)b * S * 64;
    const char* KbB = (const char*)(kb + (size_t)b * S * 64);
    const ushort_t* VtP = vt + (size_t)b * 64 * S;

    const short8 qf0 = *(const short8*)(Qb + (size_t)qrow * 64 + lg * 8);
    const short8 qf1 = *(const short8*)(Qb + (size_t)qrow * 64 + 32 + lg * 8);

    f32x4 o[4];
#pragma unroll
    for (int nt = 0; nt < 4; ++nt) o[nt] = {0.f, 0.f, 0.f, 0.f};
    float m = -1e30f, l = 0.f;

    char* PsC = (char*)&PsU[wid][0];
    const int ntiles = (qt >> 1) + 1;            // 128-wide kv tiles

    auto stage = [&](int t, int buf) {           // K only: 1024 slots of 16B
        const int kv0 = t * 128;
#pragma unroll
        for (int i = 0; i < 4; ++i) {
            const int slot = i * 256 + tid;
            const int row = slot >> 3, ch = slot & 7;
            gl_lds16(KbB + (size_t)(kv0 + row) * 128 + ((ch ^ (row & 7)) << 4),
                     (char*)&LsU[buf][0] + slot * 16);
        }
    };
    auto loadV = [&](short8* v, int ks, int kv0) {
#pragma unroll
        for (int nt = 0; nt < 4; ++nt)
            v[nt] = *(const short8*)(
                VtP + (size_t)(nt * 16 + q16) * S + kv0 + ks * 32 + lg * 8);
    };

    int buf = 0;
    if (z < ntiles) stage(z, 0);
    __syncthreads();

    for (int t = z; t < ntiles; t += SPLIT) {
        if (t + SPLIT < ntiles) stage(t + SPLIT, buf ^ 1);  // overlaps compute below
        const char* KsC = (const char*)&LsU[buf][0];
        const int kv0 = t * 128;

        // ---- S^T = K . Q^T : D[kv 128][q 16], lane q=q16, kv = kv0+16mt+4lg+r ----
        f32x4 st[8];
#pragma unroll
        for (int mt = 0; mt < 8; ++mt) st[mt] = {0.f, 0.f, 0.f, 0.f};
#pragma unroll
        for (int ks = 0; ks < 2; ++ks) {
#pragma unroll
            for (int mg = 0; mg < 2; ++mg) {
                short8 kf[4];
#pragma unroll
                for (int j = 0; j < 4; ++j) {
                    const int mt = mg * 4 + j;
                    kf[j] = *(const short8*)(
                        KsC + (mt * 16 + q16) * 128 + (((lg + 4 * ks) ^ (q16 & 7)) << 4));
                }
                __builtin_amdgcn_s_setprio(1);
#pragma unroll
                for (int j = 0; j < 4; ++j)
                    st[mg * 4 + j] = __builtin_amdgcn_mfma_f32_16x16x32_bf16(
                        kf[j], (ks ? qf1 : qf0), st[mg * 4 + j], 0, 0, 0);
                __builtin_amdgcn_s_setprio(0);
            }
        }

        short8 va[4], vb[4];
        loadV(va, 0, kv0);                 // L2 latency hides under mask+softmax

        // ---- causal mask: only the diagonal tile (t == ntiles-1) ----
        if (t == ntiles - 1) {
#pragma unroll
            for (int mt = 0; mt < 8; ++mt)
#pragma unroll
                for (int r = 0; r < 4; ++r)
                    if (kv0 + mt * 16 + (lg << 2) + r > qrow) st[mt][r] = -1e30f;
        }

        // ---- online softmax (log2 units), per q-column q16 ----
        float tm = -1e30f;
#pragma unroll
        for (int mt = 0; mt < 8; ++mt)
#pragma unroll
            for (int r = 0; r < 4; ++r) tm = fmaxf(tm, st[mt][r]);
        tm = fmaxf(tm, __shfl_xor(tm, 16));
        tm = fmaxf(tm, __shfl_xor(tm, 32));

        if (__all(tm <= m)) {
            float ps = 0.f;
#pragma unroll
            for (int mt = 0; mt < 8; ++mt)
#pragma unroll
                for (int r = 0; r < 4; ++r) {
                    const float pv = exp2f(st[mt][r] - m);
                    st[mt][r] = pv;
                    ps += pv;
                }
            ps += __shfl_xor(ps, 16);
            ps += __shfl_xor(ps, 32);
            l += ps;
        } else {
            const float mn = fmaxf(m, tm);
            const float corr = exp2f(m - mn);
            float ps = 0.f;
#pragma unroll
            for (int mt = 0; mt < 8; ++mt)
#pragma unroll
                for (int r = 0; r < 4; ++r) {
                    const float pv = exp2f(st[mt][r] - mn);
                    st[mt][r] = pv;
                    ps += pv;
                }
            ps += __shfl_xor(ps, 16);
            ps += __shfl_xor(ps, 32);
            l = l * corr + ps;
            m = mn;
            float corr_row[4];
#pragma unroll
            for (int r = 0; r < 4; ++r) corr_row[r] = __shfl(corr, (lg << 2) | r);
#pragma unroll
            for (int nt = 0; nt < 4; ++nt)
#pragma unroll
                for (int r = 0; r < 4; ++r) o[nt][r] *= corr_row[r];
        }

        loadV(vb, 1, kv0);                 // hides under P pack/write

        // ---- P (bf16) -> per-wave LDS [16q][256B], swizzled chunks ----
#pragma unroll
        for (int mt = 0; mt < 8; ++mt) {
            uint2 w;
            w.x = (unsigned)f2bf(st[mt][0]) | ((unsigned)f2bf(st[mt][1]) << 16);
            w.y = (unsigned)f2bf(st[mt][2]) | ((unsigned)f2bf(st[mt][3]) << 16);
            const int ch = (2 * mt + (lg >> 1)) ^ q16;
            *reinterpret_cast<uint2*>(PsC + q16 * 256 + ch * 16 + (lg & 1) * 8) = w;
        }

        // ---- O += P . V : 4 ks-slices of 32 kv; V 2-deep staggered ----
        __builtin_amdgcn_s_setprio(1);
        {   // ks = 0
            const short8 pa = *(const short8*)(PsC + q16 * 256 + ((lg ^ q16) << 4));
#pragma unroll
            for (int nt = 0; nt < 4; ++nt)
                o[nt] = __builtin_amdgcn_mfma_f32_16x16x32_bf16(pa, va[nt], o[nt], 0, 0, 0);
        }
        loadV(va, 2, kv0);
        {   // ks = 1
            const short8 pa = *(const short8*)(PsC + q16 * 256 + (((4 + lg) ^ q16) << 4));
#pragma unroll
            for (int nt = 0; nt < 4; ++nt)
                o[nt] = __builtin_amdgcn_mfma_f32_16x16x32_bf16(pa, vb[nt], o[nt], 0, 0, 0);
        }
        loadV(vb, 3, kv0);
        {   // ks = 2
            const short8 pa = *(const short8*)(PsC + q16 * 256 + (((8 + lg) ^ q16) << 4));
#pragma unroll
            for (int nt = 0; nt < 4; ++nt)
                o[nt] = __builtin_amdgcn_mfma_f32_16x16x32_bf16(pa, va[nt], o[nt], 0, 0, 0);
        }
        {   // ks = 3
            const short8 pa = *(const short8*)(PsC + q16 * 256 + (((12 + lg) ^ q16) << 4));
#pragma unroll
            for (int nt = 0; nt < 4; ++nt)
                o[nt] = __builtin_amdgcn_mfma_f32_16x16x32_bf16(pa, vb[nt], o[nt], 0, 0, 0);
        }
        __builtin_amdgcn_s_setprio(0);

        __syncthreads();   // drains stage vmcnt; guards K buf reuse
        buf ^= 1;
    }

    // ---- partial write: o unnormalized (bf16), (m,l) f32; each wave owns rows ----
    const int rowbase = qt * 64 + wid * 16;
    const size_t zb = (size_t)z * B * S + (size_t)b * S;
#pragma unroll
    for (int nt = 0; nt < 4; ++nt)
#pragma unroll
        for (int r = 0; r < 4; ++r)
            po[(zb + rowbase + (lg << 2) + r) * 64 + nt * 16 + q16] = f2bf(o[nt][r]);
    if (lg == 0) {
        ml[(zb + rowbase + q16) * 2 + 0] = m;
        ml[(zb + rowbase + q16) * 2 + 1] = l;
    }
}

// ---------------- merge: out = sum_z c_z * o_z / sum_z c_z * l_z ----------------
__global__ __launch_bounds__(256) void merge_kernel(
    const ushort_t* __restrict__ po, const float* __restrict__ ml,
    float* __restrict__ out)
{
    const int idx = blockIdx.x * 256 + threadIdx.x;   // 0 .. B*S*8-1
    const int row = idx >> 3, c8 = idx & 7;

    float mv[SPLIT], lv[SPLIT];
#pragma unroll
    for (int zz = 0; zz < SPLIT; ++zz) {
        const float2 t = *(const float2*)(ml + ((size_t)zz * B * S + row) * 2);
        mv[zz] = t.x; lv[zz] = t.y;
    }
    const float mm = fmaxf(fmaxf(mv[0], mv[1]), fmaxf(mv[2], mv[3]));
    float L = 0.f, cz[SPLIT];
#pragma unroll
    for (int zz = 0; zz < SPLIT; ++zz) { cz[zz] = exp2f(mv[zz] - mm); L += lv[zz] * cz[zz]; }
    const float inv = 1.0f / L;

    float acc[8];
#pragma unroll
    for (int e = 0; e < 8; ++e) acc[e] = 0.f;
#pragma unroll
    for (int zz = 0; zz < SPLIT; ++zz) {
        const uint4 pk = *(const uint4*)(po + ((size_t)zz * B * S + row) * 64 + c8 * 8);
        const unsigned w[4] = {pk.x, pk.y, pk.z, pk.w};
#pragma unroll
        for (int i = 0; i < 4; ++i) {
            acc[2 * i + 0] += cz[zz] * __uint_as_float((w[i] & 0xFFFFu) << 16);
            acc[2 * i + 1] += cz[zz] * __uint_as_float((w[i] >> 16) << 16);
        }
    }
    float4 o0 = make_float4(acc[0] * inv, acc[1] * inv, acc[2] * inv, acc[3] * inv);
    float4 o1 = make_float4(acc[4] * inv, acc[5] * inv, acc[6] * inv, acc[7] * inv);
    *(float4*)(out + (size_t)row * 64 + c8 * 8 + 0) = o0;
    *(float4*)(out + (size_t)row * 64 + c8 * 8 + 4) = o1;
}

extern "C" void kernel_launch(void* const* d_in, const int* in_sizes, int n_in,
                              void* d_out, int out_size, void* d_ws, size_t ws_size,
                              hipStream_t stream) {
    const float* x  = (const float*)d_in[0];
    const float* Wq = (const float*)d_in[1];
    const float* bq = (const float*)d_in[2];
    const float* Wk = (const float*)d_in[3];
    const float* bk = (const float*)d_in[4];
    const float* Wv = (const float*)d_in[5];
    const float* bv = (const float*)d_in[6];
    float* out = (float*)d_out;

    char* ws = (char*)d_ws;
    ushort_t* wbt = (ushort_t*)(ws + WBT_OFF);
    ushort_t* qbp = (ushort_t*)(ws + QB_OFF);
    ushort_t* kbp = (ushort_t*)(ws + KB_OFF);
    ushort_t* vtp = (ushort_t*)(ws + VT_OFF);
    float*    mlp = (float*)(ws + ML_OFF);
    ushort_t* pop = (ushort_t*)(ws + PO_OFF);

    hipLaunchKernelGGL(prep_w_kernel, dim3(192), dim3(256), 0, stream, Wq, Wk, Wv, wbt);
    hipLaunchKernelGGL(qkv_mfma_kernel, dim3(512), dim3(512), 0, stream,
                       x, wbt, bq, bk, bv, qbp, kbp, vtp);
    hipLaunchKernelGGL(attn_mfma_kernel, dim3(256, SPLIT), dim3(256), 0, stream,
                       qbp, kbp, vtp, pop, mlp);
    hipLaunchKernelGGL(merge_kernel, dim3(512), dim3(256), 0, stream, pop, mlp, out);
}

// Round 13
// 103.738 us; speedup vs baseline: 1.1253x; 1.1253x over previous
//
#include <hip/hip_runtime.h>

typedef __attribute__((ext_vector_type(4))) float f32x4;
typedef __attribute__((ext_vector_type(8))) short short8;
typedef unsigned short ushort_t;

constexpr int DM = 1024, DH = 64, S = 4096, B = 4;
// fold softmax scale 1/sqrt(64) AND log2(e) into Q so scores are in exp2 units
constexpr float QSCALE = 0.125f * 1.44269504088896340736f;
constexpr int SPLIT = 4;

// ws layout (bytes)
constexpr size_t WBT_OFF = 0;                    // Wbt: [192][1024] bf16 (W transposed)
constexpr size_t QB_OFF  = 393216;               // Qb:  [B*S][64] bf16, pre-scaled
constexpr size_t KB_OFF  = QB_OFF + 2097152;     // Kb:  [B*S][64] bf16, LINEAR
constexpr size_t VT_OFF  = KB_OFF + 2097152;     // Vtb: [B][64][S] bf16, LINEAR
constexpr size_t ML_OFF  = VT_OFF + 2097152;     // ml:  f32 [4][B*S][2]  = 512KB
constexpr size_t PO_OFF  = ML_OFF + 524288;      // po:  bf16 [4][B*S][64] = 8MB

__device__ __forceinline__ ushort_t f2bf(float f) {  // RNE f32->bf16
    unsigned u = __float_as_uint(f);
    u += 0x7FFFu + ((u >> 16) & 1u);
    return (ushort_t)(u >> 16);
}

__device__ __forceinline__ void gl_lds16(const void* g, void* l) {
    __builtin_amdgcn_global_load_lds(
        (const __attribute__((address_space(1))) unsigned int*)g,
        (__attribute__((address_space(3))) unsigned int*)l, 16, 0, 0);
}

// ---------------- prep: W fp32 [1024][64] -> Wbt bf16 [192][1024] (transposed) ----
__global__ __launch_bounds__(256) void prep_w_kernel(
    const float* __restrict__ Wq, const float* __restrict__ Wk,
    const float* __restrict__ Wv, ushort_t* __restrict__ wbt)
{
    const int n = blockIdx.x;            // 0..191 : [Q(0-63)|K(64-127)|V(128-191)]
    const int p = n >> 6, d = n & 63;
    const float* W = (p == 0) ? Wq : (p == 1) ? Wk : Wv;
    const int k0 = threadIdx.x * 4;
    ushort4 pack;
    pack.x = f2bf(W[(k0 + 0) * DH + d]);
    pack.y = f2bf(W[(k0 + 1) * DH + d]);
    pack.z = f2bf(W[(k0 + 2) * DH + d]);
    pack.w = f2bf(W[(k0 + 3) * DH + d]);
    *reinterpret_cast<ushort4*>(wbt + (size_t)n * DM + k0) = pack;
}

// ---------------- QKV projection: staged GEMM, 1024 blocks (grid-supply fix) ------
// Block = 256 thr (4 waves) on 16 rows; wave wid = n-quarter (3 nt each).
// A: register-direct per lane (lane owns row q16; 4 waves read the same 2KB/step,
// L1-shared). B: 12KB dbuf via global_load_lds (wave stages segs wid*3..wid*3+2),
// issued one step ahead; one barrier per step. 1024 blocks x 4 waves: the WHOLE
// grid is co-resident (4 blocks/CU, LDS 24KB, VGPR ~45) - 2x R11's wave supply.
__global__ __launch_bounds__(256, 4) void qkv_mfma_kernel(
    const float* __restrict__ x, const ushort_t* __restrict__ wbt,
    const float* __restrict__ bq, const float* __restrict__ bk,
    const float* __restrict__ bv,
    ushort_t* __restrict__ qb, ushort_t* __restrict__ kb, ushort_t* __restrict__ vt)
{
    __shared__ uint4 BsU[2][768];        // 2 x 12KB: [192 n][64B], 16B-chunk swz ch^(row&3)

    const int tid = threadIdx.x;
    const int wid = tid >> 6, lane = tid & 63;
    const int q16 = lane & 15, lg = lane >> 4;
    const int np = wid;
    const int r0 = blockIdx.x * 16;
    const char* wB = (const char*)wbt;

    const float* xr = x + (size_t)(r0 + q16) * DM + lg * 8;

    auto stageB = [&](int kk, int buf) {
#pragma unroll
        for (int j = 0; j < 3; ++j) {
            const int sg = np * 3 + j;   // wave-uniform seg 0..11
            gl_lds16(wB + (size_t)(sg * 16 + (lane >> 2)) * 2048 + kk * 2
                        + ((((lane & 3) ^ ((lane >> 2) & 3))) << 4),
                     (char*)&BsU[buf][0] + sg * 1024 + lane * 16);
        }
    };

    f32x4 acc[3];
#pragma unroll
    for (int j = 0; j < 3; ++j) acc[j] = {0.f, 0.f, 0.f, 0.f};

    stageB(0, 0);
    __syncthreads();

    for (int s = 0; s < 32; ++s) {
        const int buf = s & 1;
        if (s + 1 < 32) stageB((s + 1) * 32, buf ^ 1);   // overlaps compute below
        const float4 a0 = *(const float4*)(xr + s * 32);
        const float4 a1 = *(const float4*)(xr + s * 32 + 4);
        short8 Af;
        Af[0] = (short)f2bf(a0.x); Af[1] = (short)f2bf(a0.y);
        Af[2] = (short)f2bf(a0.z); Af[3] = (short)f2bf(a0.w);
        Af[4] = (short)f2bf(a1.x); Af[5] = (short)f2bf(a1.y);
        Af[6] = (short)f2bf(a1.z); Af[7] = (short)f2bf(a1.w);
        const char* BsC = (const char*)&BsU[buf][0];
        __builtin_amdgcn_s_setprio(1);
#pragma unroll
        for (int j = 0; j < 3; ++j) {
            const int nt = np * 3 + j;
            const short8 Bf = *(const short8*)(
                BsC + (nt * 16 + q16) * 64 + ((lg ^ (q16 & 3)) << 4));
            acc[j] = __builtin_amdgcn_mfma_f32_16x16x32_bf16(Af, Bf, acc[j], 0, 0, 0);
        }
        __builtin_amdgcn_s_setprio(0);
        __syncthreads();   // drains next-stage vmcnt; guards buf reuse
    }

    // Epilogue: C/D layout row=(lane>>4)*4+reg, col=lane&15. Kb/Vt LINEAR.
#pragma unroll
    for (int j = 0; j < 3; ++j) {
        const int nt = np * 3 + j;
        const int p = nt >> 2, d = ((nt & 3) << 4) + q16;
        const float* bp = (p == 0) ? bq : (p == 1) ? bk : bv;
        const float bb = bp[d];
#pragma unroll
        for (int r = 0; r < 4; ++r) {
            const int m = r0 + (lg << 2) + r;
            const float v = acc[j][r] + bb;
            if (p == 0) {
                qb[(size_t)m * 64 + d] = f2bf(v * QSCALE);
            } else if (p == 1) {
                kb[(size_t)m * 64 + d] = f2bf(v);
            } else {
                const int bb_ = m >> 12, sx = m & 4095;
                vt[(size_t)bb_ * 262144 + (size_t)d * 4096 + sx] = f2bf(v);
            }
        }
    }
}

// ---------------- causal flash attention: QBLK=64, KVBLK=128, single-buffer ------
// R11 body (proven), but K+V staging SINGLE-buffered: LDS = 32KB stage + 16KB P
// = 48KB -> 3 blocks/CU (was 80KB/2). Per tile: stage -> barrier -> compute ->
// barrier; the exposed staging drain (~500cyc) is covered by the other resident
// blocks' compute (m114 inter-block overlap), trading intra-block prefetch for
// +50% resident waves.
__global__ __launch_bounds__(256, 4) void attn_mfma_kernel(
    const ushort_t* __restrict__ qb, const ushort_t* __restrict__ kb,
    const ushort_t* __restrict__ vt, ushort_t* __restrict__ po,
    float* __restrict__ ml)
{
    __shared__ uint4 LsU[2048];        // 32KB: [K 16KB | Vt 16KB], 16B slots
    __shared__ uint4 PsU[4][256];      // 16KB: per-wave P [16 q][128 kv] bf16

    const int tid = threadIdx.x;
    const int wid = tid >> 6, lane = tid & 63;
    const int q16 = lane & 15, lg = lane >> 4;
    const int z = blockIdx.y;

    // XCD-pinned (2 XCDs per batch), heavy q-blocks first.
    const int linear = blockIdx.x;            // 0..255
    const int xcd = linear & 7, idx = linear >> 3;
    const int b = xcd >> 1;
    const int qt = 63 - (idx * 2 + (xcd & 1));   // 64-row q-block, 0..63

    const int qrow = qt * 64 + wid * 16 + q16;   // this lane's q (C/D column)
    const ushort_t* Qb = qb + (size_t)b * S * 64;
    const char* KbB = (const char*)(kb + (size_t)b * S * 64);
    const char* VtB = (const char*)(vt + (size_t)b * 64 * S);

    const short8 qf0 = *(const short8*)(Qb + (size_t)qrow * 64 + lg * 8);
    const short8 qf1 = *(const short8*)(Qb + (size_t)qrow * 64 + 32 + lg * 8);

    f32x4 o[4];
#pragma unroll
    for (int nt = 0; nt < 4; ++nt) o[nt] = {0.f, 0.f, 0.f, 0.f};
    float m = -1e30f, l = 0.f;

    char* PsC = (char*)&PsU[wid][0];
    const int ntiles = (qt >> 1) + 1;            // 128-wide kv tiles

    // Stage tile t (128 kv): K [128 rows][128B] + Vt [64 d][256B]; swizzle on source.
    auto stage = [&](int t) {
        const int kv0 = t * 128;
#pragma unroll
        for (int i = 0; i < 8; ++i) {
            const int slot = i * 256 + tid;
            char* dst = (char*)&LsU[0] + slot * 16;
            if (slot < 1024) {
                const int row = slot >> 3, ch = slot & 7;
                gl_lds16(KbB + (size_t)(kv0 + row) * 128 + ((ch ^ (row & 7)) << 4), dst);
            } else {
                const int s2 = slot - 1024;
                const int d = s2 >> 4, ch = s2 & 15;
                gl_lds16(VtB + (size_t)d * (S * 2) + kv0 * 2 + ((ch ^ (d & 15)) << 4), dst);
            }
        }
    };

    for (int t = z; t < ntiles; t += SPLIT) {
        stage(t);
        __syncthreads();                 // staged K/V visible to all waves
        const char* KsC = (const char*)&LsU[0];
        const char* VsC = KsC + 16384;
        const int kv0 = t * 128;

        // ---- S^T = K . Q^T : D[kv 128][q 16], lane q=q16, kv = kv0+16mt+4lg+r ----
        f32x4 st[8];
#pragma unroll
        for (int mt = 0; mt < 8; ++mt) st[mt] = {0.f, 0.f, 0.f, 0.f};
#pragma unroll
        for (int ks = 0; ks < 2; ++ks) {
#pragma unroll
            for (int mg = 0; mg < 2; ++mg) {
                short8 kf[4];
#pragma unroll
                for (int j = 0; j < 4; ++j) {
                    const int mt = mg * 4 + j;
                    kf[j] = *(const short8*)(
                        KsC + (mt * 16 + q16) * 128 + (((lg + 4 * ks) ^ (q16 & 7)) << 4));
                }
                __builtin_amdgcn_s_setprio(1);
#pragma unroll
                for (int j = 0; j < 4; ++j)
                    st[mg * 4 + j] = __builtin_amdgcn_mfma_f32_16x16x32_bf16(
                        kf[j], (ks ? qf1 : qf0), st[mg * 4 + j], 0, 0, 0);
                __builtin_amdgcn_s_setprio(0);
            }
        }

        // ---- causal mask: only the diagonal tile (t == ntiles-1) ----
        if (t == ntiles - 1) {
#pragma unroll
            for (int mt = 0; mt < 8; ++mt)
#pragma unroll
                for (int r = 0; r < 4; ++r)
                    if (kv0 + mt * 16 + (lg << 2) + r > qrow) st[mt][r] = -1e30f;
        }

        // ---- online softmax (log2 units), per q-column q16 ----
        float tm = -1e30f;
#pragma unroll
        for (int mt = 0; mt < 8; ++mt)
#pragma unroll
            for (int r = 0; r < 4; ++r) tm = fmaxf(tm, st[mt][r]);
        tm = fmaxf(tm, __shfl_xor(tm, 16));
        tm = fmaxf(tm, __shfl_xor(tm, 32));

        if (__all(tm <= m)) {
            // fast path: running max unchanged -> no rescale, no corr shuffles
            float ps = 0.f;
#pragma unroll
            for (int mt = 0; mt < 8; ++mt)
#pragma unroll
                for (int r = 0; r < 4; ++r) {
                    const float pv = exp2f(st[mt][r] - m);
                    st[mt][r] = pv;
                    ps += pv;
                }
            ps += __shfl_xor(ps, 16);
            ps += __shfl_xor(ps, 32);
            l += ps;
        } else {
            const float mn = fmaxf(m, tm);
            const float corr = exp2f(m - mn);
            float ps = 0.f;
#pragma unroll
            for (int mt = 0; mt < 8; ++mt)
#pragma unroll
                for (int r = 0; r < 4; ++r) {
                    const float pv = exp2f(st[mt][r] - mn);
                    st[mt][r] = pv;
                    ps += pv;
                }
            ps += __shfl_xor(ps, 16);
            ps += __shfl_xor(ps, 32);
            l = l * corr + ps;
            m = mn;
            // o rows are q = 4lg+r but corr is per q-col q16 -> redistribute.
            float corr_row[4];
#pragma unroll
            for (int r = 0; r < 4; ++r) corr_row[r] = __shfl(corr, (lg << 2) | r);
#pragma unroll
            for (int nt = 0; nt < 4; ++nt)
#pragma unroll
                for (int r = 0; r < 4; ++r) o[nt][r] *= corr_row[r];
        }

        // ---- P (bf16) -> per-wave LDS [16q][256B], swizzled chunks ----
#pragma unroll
        for (int mt = 0; mt < 8; ++mt) {
            uint2 w;
            w.x = (unsigned)f2bf(st[mt][0]) | ((unsigned)f2bf(st[mt][1]) << 16);
            w.y = (unsigned)f2bf(st[mt][2]) | ((unsigned)f2bf(st[mt][3]) << 16);
            const int ch = (2 * mt + (lg >> 1)) ^ q16;
            *reinterpret_cast<uint2*>(PsC + q16 * 256 + ch * 16 + (lg & 1) * 8) = w;
        }

        // ---- O += P . V : D[q][d], 4 ks-slices of 32 kv ----
        __builtin_amdgcn_s_setprio(1);
#pragma unroll
        for (int ks = 0; ks < 4; ++ks) {
            const short8 pa = *reinterpret_cast<const short8*>(
                PsC + q16 * 256 + (((4 * ks + lg) ^ q16) << 4));
#pragma unroll
            for (int nt = 0; nt < 4; ++nt) {
                const short8 vf = *(const short8*)(
                    VsC + (nt * 16 + q16) * 256 + (((ks * 4 + lg) ^ q16) << 4));
                o[nt] = __builtin_amdgcn_mfma_f32_16x16x32_bf16(pa, vf, o[nt], 0, 0, 0);
            }
        }
        __builtin_amdgcn_s_setprio(0);

        __syncthreads();   // all waves done reading before next stage overwrites
    }

    // ---- partial write: o unnormalized (bf16), (m,l) f32; each wave owns rows ----
    const int rowbase = qt * 64 + wid * 16;
    const size_t zb = (size_t)z * B * S + (size_t)b * S;
#pragma unroll
    for (int nt = 0; nt < 4; ++nt)
#pragma unroll
        for (int r = 0; r < 4; ++r)
            po[(zb + rowbase + (lg << 2) + r) * 64 + nt * 16 + q16] = f2bf(o[nt][r]);
    if (lg == 0) {
        ml[(zb + rowbase + q16) * 2 + 0] = m;
        ml[(zb + rowbase + q16) * 2 + 1] = l;
    }
}

// ---------------- merge: out = sum_z c_z * o_z / sum_z c_z * l_z ----------------
__global__ __launch_bounds__(256) void merge_kernel(
    const ushort_t* __restrict__ po, const float* __restrict__ ml,
    float* __restrict__ out)
{
    const int idx = blockIdx.x * 256 + threadIdx.x;   // 0 .. B*S*8-1
    const int row = idx >> 3, c8 = idx & 7;

    float mv[SPLIT], lv[SPLIT];
#pragma unroll
    for (int zz = 0; zz < SPLIT; ++zz) {
        const float2 t = *(const float2*)(ml + ((size_t)zz * B * S + row) * 2);
        mv[zz] = t.x; lv[zz] = t.y;
    }
    const float mm = fmaxf(fmaxf(mv[0], mv[1]), fmaxf(mv[2], mv[3]));
    float L = 0.f, cz[SPLIT];
#pragma unroll
    for (int zz = 0; zz < SPLIT; ++zz) { cz[zz] = exp2f(mv[zz] - mm); L += lv[zz] * cz[zz]; }
    const float inv = 1.0f / L;

    float acc[8];
#pragma unroll
    for (int e = 0; e < 8; ++e) acc[e] = 0.f;
#pragma unroll
    for (int zz = 0; zz < SPLIT; ++zz) {
        const uint4 pk = *(const uint4*)(po + ((size_t)zz * B * S + row) * 64 + c8 * 8);
        const unsigned w[4] = {pk.x, pk.y, pk.z, pk.w};
#pragma unroll
        for (int i = 0; i < 4; ++i) {
            acc[2 * i + 0] += cz[zz] * __uint_as_float((w[i] & 0xFFFFu) << 16);
            acc[2 * i + 1] += cz[zz] * __uint_as_float((w[i] >> 16) << 16);
        }
    }
    float4 o0 = make_float4(acc[0] * inv, acc[1] * inv, acc[2] * inv, acc[3] * inv);
    float4 o1 = make_float4(acc[4] * inv, acc[5] * inv, acc[6] * inv, acc[7] * inv);
    *(float4*)(out + (size_t)row * 64 + c8 * 8 + 0) = o0;
    *(float4*)(out + (size_t)row * 64 + c8 * 8 + 4) = o1;
}

extern "C" void kernel_launch(void* const* d_in, const int* in_sizes, int n_in,
                              void* d_out, int out_size, void* d_ws, size_t ws_size,
                              hipStream_t stream) {
    const float* x  = (const float*)d_in[0];
    const float* Wq = (const float*)d_in[1];
    const float* bq = (const float*)d_in[2];
    const float* Wk = (const float*)d_in[3];
    const float* bk = (const float*)d_in[4];
    const float* Wv = (const float*)d_in[5];
    const float* bv = (const float*)d_in[6];
    float* out = (float*)d_out;

    char* ws = (char*)d_ws;
    ushort_t* wbt = (ushort_t*)(ws + WBT_OFF);
    ushort_t* qbp = (ushort_t*)(ws + QB_OFF);
    ushort_t* kbp = (ushort_t*)(ws + KB_OFF);
    ushort_t* vtp = (ushort_t*)(ws + VT_OFF);
    float*    mlp = (float*)(ws + ML_OFF);
    ushort_t* pop = (ushort_t*)(ws + PO_OFF);

    hipLaunchKernelGGL(prep_w_kernel, dim3(192), dim3(256), 0, stream, Wq, Wk, Wv, wbt);
    hipLaunchKernelGGL(qkv_mfma_kernel, dim3(1024), dim3(256), 0, stream,
                       x, wbt, bq, bk, bv, qbp, kbp, vtp);
    hipLaunchKernelGGL(attn_mfma_kernel, dim3(256, SPLIT), dim3(256), 0, stream,
                       qbp, kbp, vtp, pop, mlp);
    hipLaunchKernelGGL(merge_kernel, dim3(512), dim3(256), 0, stream, pop, mlp, out);
}

// Round 14
// 91.764 us; speedup vs baseline: 1.2722x; 1.1305x over previous
//
#include <hip/hip_runtime.h>

typedef __attribute__((ext_vector_type(4))) float f32x4;
typedef __attribute__((ext_vector_type(8))) short short8;
typedef unsigned short ushort_t;

constexpr int DM = 1024, DH = 64, S = 4096, B = 4;
// fold softmax scale 1/sqrt(64) AND log2(e) into Q so scores are in exp2 units
constexpr float QSCALE = 0.125f * 1.44269504088896340736f;
constexpr int SPLIT = 4;

// ws layout (bytes)
constexpr size_t WBT_OFF = 0;                    // Wbt: [192][1024] bf16 (W transposed)
constexpr size_t QB_OFF  = 393216;               // Qb:  [B*S][64] bf16, pre-scaled
constexpr size_t KB_OFF  = QB_OFF + 2097152;     // Kb:  [B*S][64] bf16, LINEAR
constexpr size_t VT_OFF  = KB_OFF + 2097152;     // Vtb: [B][64][S] bf16, LINEAR
constexpr size_t ML_OFF  = VT_OFF + 2097152;     // ml:  f32 [4][B*S][2]  = 512KB
constexpr size_t PO_OFF  = ML_OFF + 524288;      // po:  bf16 [4][B*S][64] = 8MB

__device__ __forceinline__ ushort_t f2bf(float f) {  // RNE f32->bf16
    unsigned u = __float_as_uint(f);
    u += 0x7FFFu + ((u >> 16) & 1u);
    return (ushort_t)(u >> 16);
}

__device__ __forceinline__ void gl_lds16(const void* g, void* l) {
    __builtin_amdgcn_global_load_lds(
        (const __attribute__((address_space(1))) unsigned int*)g,
        (__attribute__((address_space(3))) unsigned int*)l, 16, 0, 0);
}

// ---------------- prep: W fp32 [1024][64] -> Wbt bf16 [192][1024] (transposed) ----
__global__ __launch_bounds__(256) void prep_w_kernel(
    const float* __restrict__ Wq, const float* __restrict__ Wk,
    const float* __restrict__ Wv, ushort_t* __restrict__ wbt)
{
    const int n = blockIdx.x;            // 0..191 : [Q(0-63)|K(64-127)|V(128-191)]
    const int p = n >> 6, d = n & 63;
    const float* W = (p == 0) ? Wq : (p == 1) ? Wk : Wv;
    const int k0 = threadIdx.x * 4;
    ushort4 pack;
    pack.x = f2bf(W[(k0 + 0) * DH + d]);
    pack.y = f2bf(W[(k0 + 1) * DH + d]);
    pack.z = f2bf(W[(k0 + 2) * DH + d]);
    pack.w = f2bf(W[(k0 + 3) * DH + d]);
    *reinterpret_cast<ushort4*>(wbt + (size_t)n * DM + k0) = pack;
}

// ---------------- QKV projection: staged GEMM, K-step 64 (16 steps) --------------
// Block = 512 thr (8 waves) on 32 rows; wave = (sub = m-half, np = n-quarter).
// A: register-direct per lane (lane owns row sub*16+q16; 4 float4 per step).
// B: 24KB/step dbuf via global_load_lds (3 segs/wave; seg = 8 n-rows x 128B),
// issued one step ahead; one barrier per step. K-step 64 -> only 16 barrier
// drains (R9-R13 ledger: the per-step drain, not VALU or BW, pins qkv at ~35us
// with 32 steps). 6 MFMA/wave/step. LDS 48KB; VGPR ~60.
__global__ __launch_bounds__(512, 4) void qkv_mfma_kernel(
    const float* __restrict__ x, const ushort_t* __restrict__ wbt,
    const float* __restrict__ bq, const float* __restrict__ bk,
    const float* __restrict__ bv,
    ushort_t* __restrict__ qb, ushort_t* __restrict__ kb, ushort_t* __restrict__ vt)
{
    __shared__ uint4 BsU[2][1536];       // 2 x 24KB: [192 n][128B], 16B-chunk swz ch^(row&7)

    const int tid = threadIdx.x;
    const int wid = tid >> 6, lane = tid & 63;
    const int q16 = lane & 15, lg = lane >> 4;
    const int sub = wid & 1, np = wid >> 1;
    const int r0 = blockIdx.x * 32;
    const char* wB = (const char*)wbt;

    const float* xr = x + (size_t)(r0 + sub * 16 + q16) * DM;

    // stage B k-slice [s*64, s*64+64): 24 segs of 1KB (8 n-rows x 128B); 3 per wave
    auto stageB = [&](int s, int buf) {
#pragma unroll
        for (int j = 0; j < 3; ++j) {
            const int sg = wid * 3 + j;              // wave-uniform 0..23
            const int row = sg * 8 + (lane >> 3);    // n-row
            const int ch = lane & 7;                 // 16B chunk in the 128B row-slice
            gl_lds16(wB + (size_t)row * 2048 + s * 128 + ((ch ^ (row & 7)) << 4),
                     (char*)&BsU[buf][0] + sg * 1024 + lane * 16);
        }
    };

    f32x4 acc[3];
#pragma unroll
    for (int j = 0; j < 3; ++j) acc[j] = {0.f, 0.f, 0.f, 0.f};

    stageB(0, 0);
    __syncthreads();

    for (int s = 0; s < 16; ++s) {
        const int buf = s & 1;
        if (s + 1 < 16) stageB(s + 1, buf ^ 1);      // overlaps compute below
        const float4 a0 = *(const float4*)(xr + s * 64 + lg * 8);
        const float4 a1 = *(const float4*)(xr + s * 64 + lg * 8 + 4);
        const float4 a2 = *(const float4*)(xr + s * 64 + 32 + lg * 8);
        const float4 a3 = *(const float4*)(xr + s * 64 + 32 + lg * 8 + 4);
        short8 Af0, Af1;
        Af0[0] = (short)f2bf(a0.x); Af0[1] = (short)f2bf(a0.y);
        Af0[2] = (short)f2bf(a0.z); Af0[3] = (short)f2bf(a0.w);
        Af0[4] = (short)f2bf(a1.x); Af0[5] = (short)f2bf(a1.y);
        Af0[6] = (short)f2bf(a1.z); Af0[7] = (short)f2bf(a1.w);
        Af1[0] = (short)f2bf(a2.x); Af1[1] = (short)f2bf(a2.y);
        Af1[2] = (short)f2bf(a2.z); Af1[3] = (short)f2bf(a2.w);
        Af1[4] = (short)f2bf(a3.x); Af1[5] = (short)f2bf(a3.y);
        Af1[6] = (short)f2bf(a3.z); Af1[7] = (short)f2bf(a3.w);
        const char* BsC = (const char*)&BsU[buf][0];
        __builtin_amdgcn_s_setprio(1);
#pragma unroll
        for (int j = 0; j < 3; ++j) {
            const int nt = np * 3 + j;
            const int rn = nt * 16 + q16;
            const short8 Bf0 = *(const short8*)(
                BsC + rn * 128 + ((lg ^ (q16 & 7)) << 4));
            acc[j] = __builtin_amdgcn_mfma_f32_16x16x32_bf16(Af0, Bf0, acc[j], 0, 0, 0);
            const short8 Bf1 = *(const short8*)(
                BsC + rn * 128 + (((4 + lg) ^ (q16 & 7)) << 4));
            acc[j] = __builtin_amdgcn_mfma_f32_16x16x32_bf16(Af1, Bf1, acc[j], 0, 0, 0);
        }
        __builtin_amdgcn_s_setprio(0);
        __syncthreads();   // drains next-stage vmcnt; guards buf reuse
    }

    // Epilogue: C/D layout row=(lane>>4)*4+reg, col=lane&15. Kb/Vt LINEAR.
#pragma unroll
    for (int j = 0; j < 3; ++j) {
        const int nt = np * 3 + j;
        const int p = nt >> 2, d = ((nt & 3) << 4) + q16;
        const float* bp = (p == 0) ? bq : (p == 1) ? bk : bv;
        const float bb = bp[d];
#pragma unroll
        for (int r = 0; r < 4; ++r) {
            const int m = r0 + sub * 16 + (lg << 2) + r;
            const float v = acc[j][r] + bb;
            if (p == 0) {
                qb[(size_t)m * 64 + d] = f2bf(v * QSCALE);
            } else if (p == 1) {
                kb[(size_t)m * 64 + d] = f2bf(v);
            } else {
                const int bb_ = m >> 12, sx = m & 4095;
                vt[(size_t)bb_ * 262144 + (size_t)d * 4096 + sx] = f2bf(v);
            }
        }
    }
}

// ---------------- causal flash attention: QBLK=64, KVBLK=128, split-KV x4 ----------
// Exact R11 body (proven 43us profiled / ~33.5us graph).
__global__ __launch_bounds__(256, 4) void attn_mfma_kernel(
    const ushort_t* __restrict__ qb, const ushort_t* __restrict__ kb,
    const ushort_t* __restrict__ vt, ushort_t* __restrict__ po,
    float* __restrict__ ml)
{
    __shared__ uint4 LsU[2][2048];     // 64KB: [buf][K 16KB | Vt 16KB], 16B slots
    __shared__ uint4 PsU[4][256];      // 16KB: per-wave P [16 q][128 kv] bf16

    const int tid = threadIdx.x;
    const int wid = tid >> 6, lane = tid & 63;
    const int q16 = lane & 15, lg = lane >> 4;
    const int z = blockIdx.y;

    // XCD-pinned (2 XCDs per batch), heavy q-blocks first.
    const int linear = blockIdx.x;            // 0..255
    const int xcd = linear & 7, idx = linear >> 3;
    const int b = xcd >> 1;
    const int qt = 63 - (idx * 2 + (xcd & 1));   // 64-row q-block, 0..63

    const int qrow = qt * 64 + wid * 16 + q16;   // this lane's q (C/D column)
    const ushort_t* Qb = qb + (size_t)b * S * 64;
    const char* KbB = (const char*)(kb + (size_t)b * S * 64);
    const char* VtB = (const char*)(vt + (size_t)b * 64 * S);

    const short8 qf0 = *(const short8*)(Qb + (size_t)qrow * 64 + lg * 8);
    const short8 qf1 = *(const short8*)(Qb + (size_t)qrow * 64 + 32 + lg * 8);

    f32x4 o[4];
#pragma unroll
    for (int nt = 0; nt < 4; ++nt) o[nt] = {0.f, 0.f, 0.f, 0.f};
    float m = -1e30f, l = 0.f;

    char* PsC = (char*)&PsU[wid][0];
    const int ntiles = (qt >> 1) + 1;            // 128-wide kv tiles

    // Stage tile t (128 kv): K [128 rows][128B] + Vt [64 d][256B]; swizzle on source.
    auto stage = [&](int t, int buf) {
        const int kv0 = t * 128;
#pragma unroll
        for (int i = 0; i < 8; ++i) {
            const int slot = i * 256 + tid;
            char* dst = (char*)&LsU[buf][0] + slot * 16;
            if (slot < 1024) {
                const int row = slot >> 3, ch = slot & 7;
                gl_lds16(KbB + (size_t)(kv0 + row) * 128 + ((ch ^ (row & 7)) << 4), dst);
            } else {
                const int s2 = slot - 1024;
                const int d = s2 >> 4, ch = s2 & 15;
                gl_lds16(VtB + (size_t)d * (S * 2) + kv0 * 2 + ((ch ^ (d & 15)) << 4), dst);
            }
        }
    };

    int buf = 0;
    if (z < ntiles) stage(z, 0);
    __syncthreads();

    for (int t = z; t < ntiles; t += SPLIT) {
        if (t + SPLIT < ntiles) stage(t + SPLIT, buf ^ 1);  // overlaps compute below
        const char* KsC = (const char*)&LsU[buf][0];
        const char* VsC = KsC + 16384;
        const int kv0 = t * 128;

        // ---- S^T = K . Q^T : D[kv 128][q 16], lane q=q16, kv = kv0+16mt+4lg+r ----
        f32x4 st[8];
#pragma unroll
        for (int mt = 0; mt < 8; ++mt) st[mt] = {0.f, 0.f, 0.f, 0.f};
#pragma unroll
        for (int ks = 0; ks < 2; ++ks) {
#pragma unroll
            for (int mg = 0; mg < 2; ++mg) {
                short8 kf[4];
#pragma unroll
                for (int j = 0; j < 4; ++j) {
                    const int mt = mg * 4 + j;
                    kf[j] = *(const short8*)(
                        KsC + (mt * 16 + q16) * 128 + (((lg + 4 * ks) ^ (q16 & 7)) << 4));
                }
                __builtin_amdgcn_s_setprio(1);
#pragma unroll
                for (int j = 0; j < 4; ++j)
                    st[mg * 4 + j] = __builtin_amdgcn_mfma_f32_16x16x32_bf16(
                        kf[j], (ks ? qf1 : qf0), st[mg * 4 + j], 0, 0, 0);
                __builtin_amdgcn_s_setprio(0);
            }
        }

        // ---- causal mask: only the diagonal tile (t == ntiles-1) ----
        if (t == ntiles - 1) {
#pragma unroll
            for (int mt = 0; mt < 8; ++mt)
#pragma unroll
                for (int r = 0; r < 4; ++r)
                    if (kv0 + mt * 16 + (lg << 2) + r > qrow) st[mt][r] = -1e30f;
        }

        // ---- online softmax (log2 units), per q-column q16 ----
        float tm = -1e30f;
#pragma unroll
        for (int mt = 0; mt < 8; ++mt)
#pragma unroll
            for (int r = 0; r < 4; ++r) tm = fmaxf(tm, st[mt][r]);
        tm = fmaxf(tm, __shfl_xor(tm, 16));
        tm = fmaxf(tm, __shfl_xor(tm, 32));

        if (__all(tm <= m)) {
            // fast path: running max unchanged -> no rescale, no corr shuffles
            float ps = 0.f;
#pragma unroll
            for (int mt = 0; mt < 8; ++mt)
#pragma unroll
                for (int r = 0; r < 4; ++r) {
                    const float pv = exp2f(st[mt][r] - m);
                    st[mt][r] = pv;
                    ps += pv;
                }
            ps += __shfl_xor(ps, 16);
            ps += __shfl_xor(ps, 32);
            l += ps;
        } else {
            const float mn = fmaxf(m, tm);
            const float corr = exp2f(m - mn);
            float ps = 0.f;
#pragma unroll
            for (int mt = 0; mt < 8; ++mt)
#pragma unroll
                for (int r = 0; r < 4; ++r) {
                    const float pv = exp2f(st[mt][r] - mn);
                    st[mt][r] = pv;
                    ps += pv;
                }
            ps += __shfl_xor(ps, 16);
            ps += __shfl_xor(ps, 32);
            l = l * corr + ps;
            m = mn;
            // o rows are q = 4lg+r but corr is per q-col q16 -> redistribute.
            float corr_row[4];
#pragma unroll
            for (int r = 0; r < 4; ++r) corr_row[r] = __shfl(corr, (lg << 2) | r);
#pragma unroll
            for (int nt = 0; nt < 4; ++nt)
#pragma unroll
                for (int r = 0; r < 4; ++r) o[nt][r] *= corr_row[r];
        }

        // ---- P (bf16) -> per-wave LDS [16q][256B], swizzled chunks ----
#pragma unroll
        for (int mt = 0; mt < 8; ++mt) {
            uint2 w;
            w.x = (unsigned)f2bf(st[mt][0]) | ((unsigned)f2bf(st[mt][1]) << 16);
            w.y = (unsigned)f2bf(st[mt][2]) | ((unsigned)f2bf(st[mt][3]) << 16);
            const int ch = (2 * mt + (lg >> 1)) ^ q16;
            *reinterpret_cast<uint2*>(PsC + q16 * 256 + ch * 16 + (lg & 1) * 8) = w;
        }

        // ---- O += P . V : D[q][d], 4 ks-slices of 32 kv ----
        __builtin_amdgcn_s_setprio(1);
#pragma unroll
        for (int ks = 0; ks < 4; ++ks) {
            const short8 pa = *reinterpret_cast<const short8*>(
                PsC + q16 * 256 + (((4 * ks + lg) ^ q16) << 4));
#pragma unroll
            for (int nt = 0; nt < 4; ++nt) {
                const short8 vf = *(const short8*)(
                    VsC + (nt * 16 + q16) * 256 + (((ks * 4 + lg) ^ q16) << 4));
                o[nt] = __builtin_amdgcn_mfma_f32_16x16x32_bf16(pa, vf, o[nt], 0, 0, 0);
            }
        }
        __builtin_amdgcn_s_setprio(0);

        __syncthreads();   // drains stage vmcnt; guards buf reuse
        buf ^= 1;
    }

    // ---- partial write: o unnormalized (bf16), (m,l) f32; each wave owns rows ----
    const int rowbase = qt * 64 + wid * 16;
    const size_t zb = (size_t)z * B * S + (size_t)b * S;
#pragma unroll
    for (int nt = 0; nt < 4; ++nt)
#pragma unroll
        for (int r = 0; r < 4; ++r)
            po[(zb + rowbase + (lg << 2) + r) * 64 + nt * 16 + q16] = f2bf(o[nt][r]);
    if (lg == 0) {
        ml[(zb + rowbase + q16) * 2 + 0] = m;
        ml[(zb + rowbase + q16) * 2 + 1] = l;
    }
}

// ---------------- merge: out = sum_z c_z * o_z / sum_z c_z * l_z ----------------
__global__ __launch_bounds__(256) void merge_kernel(
    const ushort_t* __restrict__ po, const float* __restrict__ ml,
    float* __restrict__ out)
{
    const int idx = blockIdx.x * 256 + threadIdx.x;   // 0 .. B*S*8-1
    const int row = idx >> 3, c8 = idx & 7;

    float mv[SPLIT], lv[SPLIT];
#pragma unroll
    for (int zz = 0; zz < SPLIT; ++zz) {
        const float2 t = *(const float2*)(ml + ((size_t)zz * B * S + row) * 2);
        mv[zz] = t.x; lv[zz] = t.y;
    }
    const float mm = fmaxf(fmaxf(mv[0], mv[1]), fmaxf(mv[2], mv[3]));
    float L = 0.f, cz[SPLIT];
#pragma unroll
    for (int zz = 0; zz < SPLIT; ++zz) { cz[zz] = exp2f(mv[zz] - mm); L += lv[zz] * cz[zz]; }
    const float inv = 1.0f / L;

    float acc[8];
#pragma unroll
    for (int e = 0; e < 8; ++e) acc[e] = 0.f;
#pragma unroll
    for (int zz = 0; zz < SPLIT; ++zz) {
        const uint4 pk = *(const uint4*)(po + ((size_t)zz * B * S + row) * 64 + c8 * 8);
        const unsigned w[4] = {pk.x, pk.y, pk.z, pk.w};
#pragma unroll
        for (int i = 0; i < 4; ++i) {
            acc[2 * i + 0] += cz[zz] * __uint_as_float((w[i] & 0xFFFFu) << 16);
            acc[2 * i + 1] += cz[zz] * __uint_as_float((w[i] >> 16) << 16);
        }
    }
    float4 o0 = make_float4(acc[0] * inv, acc[1] * inv, acc[2] * inv, acc[3] * inv);
    float4 o1 = make_float4(acc[4] * inv, acc[5] * inv, acc[6] * inv, acc[7] * inv);
    *(float4*)(out + (size_t)row * 64 + c8 * 8 + 0) = o0;
    *(float4*)(out + (size_t)row * 64 + c8 * 8 + 4) = o1;
}

extern "C" void kernel_launch(void* const* d_in, const int* in_sizes, int n_in,
                              void* d_out, int out_size, void* d_ws, size_t ws_size,
                              hipStream_t stream) {
    const float* x  = (const float*)d_in[0];
    const float* Wq = (const float*)d_in[1];
    const float* bq = (const float*)d_in[2];
    const float* Wk = (const float*)d_in[3];
    const float* bk = (const float*)d_in[4];
    const float* Wv = (const float*)d_in[5];
    const float* bv = (const float*)d_in[6];
    float* out = (float*)d_out;

    char* ws = (char*)d_ws;
    ushort_t* wbt = (ushort_t*)(ws + WBT_OFF);
    ushort_t* qbp = (ushort_t*)(ws + QB_OFF);
    ushort_t* kbp = (ushort_t*)(ws + KB_OFF);
    ushort_t* vtp = (ushort_t*)(ws + VT_OFF);
    float*    mlp = (float*)(ws + ML_OFF);
    ushort_t* pop = (ushort_t*)(ws + PO_OFF);

    hipLaunchKernelGGL(prep_w_kernel, dim3(192), dim3(256), 0, stream, Wq, Wk, Wv, wbt);
    hipLaunchKernelGGL(qkv_mfma_kernel, dim3(512), dim3(512), 0, stream,
                       x, wbt, bq, bk, bv, qbp, kbp, vtp);
    hipLaunchKernelGGL(attn_mfma_kernel, dim3(256, SPLIT), dim3(256), 0, stream,
                       qbp, kbp, vtp, pop, mlp);
    hipLaunchKernelGGL(merge_kernel, dim3(512), dim3(256), 0, stream, pop, mlp, out);
}